// Round 2
// baseline (276.001 us; speedup 1.0000x reference)
//
#include <hip/hip_runtime.h>
#include <math.h>

// Problem: B=2048 rows, L=16384, sliding window W=30 mean of sigmoid(x)*mask,
// max over window starts per row. Memory-bound: 268 MB read -> ~43 us floor.
constexpr int Bn    = 2048;
constexpr int L     = 16384;
constexpr int W     = 30;
constexpr int NWIN  = L - W + 1;        // 16355
constexpr int NT    = 256;              // threads per block
constexpr int TILE  = 2048;             // window starts per block
constexpr int TPB   = L / TILE;         // 8 tiles (blocks) per row
constexpr int NELEM = TILE + W - 1;     // 2077 staged elements (full tile)
constexpr int SPT   = TILE / NT;        // 8 window starts per thread

// LDS pad: +1 float per 8 (9-float groups). Read base for lane t is
// pidx(8t)=9t -> 9t mod 32 distinct over 32 lanes (gcd(9,32)=1): conflict-free
// within 32 lanes, 2-way across half-wave (free per m136).
__device__ __forceinline__ int pidx(int j) { return j + (j >> 3); }

__device__ __forceinline__ float sigp(float xv, float mv) {
    return mv * __builtin_amdgcn_rcpf(1.0f + __expf(-xv));
}

__global__ __launch_bounds__(NT, 6)   // cap VGPR ~85 -> 6 blocks/CU (24 waves)
void winmax_tile(const float* __restrict__ x,
                 const float* __restrict__ m,
                 float* __restrict__ out) {
    __shared__ float prob[NELEM + (NELEM >> 3) + 1];   // 2336 floats = 9.3 KiB

    const int b    = blockIdx.x;
    const int row  = b >> 3;            // TPB = 8
    const int tile = b & 7;
    const int t    = threadIdx.x;
    const int ts   = tile * TILE;                   // first window start of tile
    const int n_elems  = min(NELEM, L - ts);        // 2077; 2048 for last tile
    const int n_starts = min(TILE, NWIN - ts);      // 2048; 2019 for last tile

    const float* xr = x + (size_t)row * L + ts;
    const float* mr = m + (size_t)row * L + ts;

    // ---- Stage: main 2048 elements via coalesced float4 ----
    const float4* x4 = (const float4*)xr;
    const float4* m4 = (const float4*)mr;
    #pragma unroll
    for (int k = 0; k < TILE / (4 * NT); ++k) {     // 2 iterations
        const int vi = k * NT + t;
        const float4 xv = x4[vi];
        const float4 mv = m4[vi];
        const int j = vi * 4;                       // j%4==0 -> all 4 in one 8-group
        const int p = pidx(j);
        prob[p + 0] = sigp(xv.x, mv.x);
        prob[p + 1] = sigp(xv.y, mv.y);
        prob[p + 2] = sigp(xv.z, mv.z);
        prob[p + 3] = sigp(xv.w, mv.w);
    }
    // ---- Stage: 29-element overlap tail (skipped on last tile) ----
    {
        const int j = TILE + t;
        if (j < n_elems)
            prob[pidx(j)] = sigp(xr[j], mr[j]);
    }
    __syncthreads();

    // ---- Sliding windows: thread t owns local starts [8t, 8t+7] ----
    const int ls0 = t * SPT;
    const int nw  = min(SPT, n_starts - ls0);       // <=0 for idle tail threads
    float best = 0.0f;                              // win_mean >= 0 always
    if (nw > 0) {
        float keep[SPT - 1];                        // first 7 probs, for subtraction
        float sum = 0.0f;
        #pragma unroll
        for (int i = 0; i < W; ++i) {
            const float v = prob[pidx(ls0 + i)];
            if (i < SPT - 1) keep[i] = v;
            sum += v;
        }
        best = sum;
        #pragma unroll
        for (int i = 1; i < SPT; ++i) {
            if (i < nw) {
                sum += prob[pidx(ls0 + W - 1 + i)] - keep[i - 1];
                best = fmaxf(best, sum);
            }
        }
        best *= (1.0f / W);
    }

    // ---- Wave max-reduce, then one atomic per wave ----
    #pragma unroll
    for (int off = 32; off > 0; off >>= 1)
        best = fmaxf(best, __shfl_down(best, off, 64));
    if ((t & 63) == 0) {
        // win_mean >= 0: positive-float bits are monotone as uint -> atomicMax ok.
        atomicMax((unsigned int*)(out + row), __float_as_uint(best));
    }
}

extern "C" void kernel_launch(void* const* d_in, const int* in_sizes, int n_in,
                              void* d_out, int out_size, void* d_ws, size_t ws_size,
                              hipStream_t stream) {
    const float* x = (const float*)d_in[0];
    const float* m = (const float*)d_in[1];
    float* out = (float*)d_out;
    // out is re-poisoned to 0xAA before every launch; atomicMax needs 0-init.
    hipMemsetAsync(out, 0, Bn * sizeof(float), stream);
    winmax_tile<<<Bn * TPB, NT, 0, stream>>>(x, m, out);
}

// Round 3
// 271.161 us; speedup vs baseline: 1.0178x; 1.0178x over previous
//
#include <hip/hip_runtime.h>
#include <math.h>

// B=2048 rows, L=16384, W=30 sliding mean of sigmoid(x)*mask, per-row max.
constexpr int Bn    = 2048;
constexpr int L     = 16384;
constexpr int W     = 30;
constexpr int NWIN  = L - W + 1;        // 16355
constexpr int NT    = 256;
constexpr int TILE  = 4096;             // window starts per block
constexpr int TPB   = L / TILE;         // 4 blocks per row
constexpr int NELEM = TILE + W - 1;     // 4125 staged elements
constexpr int SPT   = TILE / NT;        // 16 window starts per thread

// LDS pad +1 float per 8. Read base for lane t: pidx(16t) = 18t ->
// 18t mod 32 = 16 distinct even residues over t=0..15, 2-way across
// half-wave: free (m136). Offsets pidx(16t+c)-18t = c+(c>>3): compile-time.
__device__ __forceinline__ int pidx(int j) { return j + (j >> 3); }

__device__ __forceinline__ float sigp(float xv, float mv) {
    // m * 1/(1 + 2^(-x*log2(e))) : v_mul, v_exp, v_add, v_rcp, v_mul
    float t = -1.44269504089f * xv;
    float e;
    asm("v_exp_f32 %0, %1" : "=v"(e) : "v"(t));
    return mv * __builtin_amdgcn_rcpf(1.0f + e);
}

__global__ __launch_bounds__(NT)
void winmax_tile(const float* __restrict__ x,
                 const float* __restrict__ m,
                 float* __restrict__ out) {
    __shared__ float prob[NELEM + (NELEM >> 3) + 2];   // 4641 floats = 18.6 KiB

    const int b    = blockIdx.x;
    const int row  = b >> 2;            // TPB = 4
    const int tile = b & 3;
    const int t    = threadIdx.x;
    const int ts   = tile * TILE;

    const float* xr = x + (size_t)row * L + ts;
    const float* mr = m + (size_t)row * L + ts;

    // ---- Stage main TILE elements: coalesced float4, all loads issued early ----
    const float4* x4 = (const float4*)xr;
    const float4* m4 = (const float4*)mr;
    float4 xv[TILE / (4 * NT)], mv[TILE / (4 * NT)];   // 4 each
    #pragma unroll
    for (int k = 0; k < TILE / (4 * NT); ++k) { xv[k] = x4[k * NT + t]; mv[k] = m4[k * NT + t]; }
    #pragma unroll
    for (int k = 0; k < TILE / (4 * NT); ++k) {
        const int j = (k * NT + t) * 4;
        const int p = pidx(j);                          // j%4==0 -> contiguous 4
        prob[p + 0] = sigp(xv[k].x, mv[k].x);
        prob[p + 1] = sigp(xv[k].y, mv[k].y);
        prob[p + 2] = sigp(xv[k].z, mv[k].z);
        prob[p + 3] = sigp(xv[k].w, mv[k].w);
    }
    // ---- Halo: W-1=29 elements past the tile; zero-fill on the last tile.
    // Truncated-window sums are subsets of the valid window at L-30 (all
    // terms >= 0), so zeros can never win the row max.
    if (t < W - 1) {
        const int j = TILE + t;
        prob[pidx(j)] = (ts + j < L) ? sigp(xr[j], mr[j]) : 0.0f;
    }
    __syncthreads();

    // ---- Sliding windows: thread t owns starts [16t, 16t+15], branch-free ----
    const int base = 18 * t;            // = pidx(16t)
    float keep[SPT - 1];
    float sum = 0.0f;
    #pragma unroll
    for (int c = 0; c < W; ++c) {       // offsets compile-time: c + (c>>3)
        const float v = prob[base + c + (c >> 3)];
        if (c < SPT - 1) keep[c] = v;
        sum += v;
    }
    float best = sum;
    #pragma unroll
    for (int i = 1; i < SPT; ++i) {
        const int c = W - 1 + i;
        sum += prob[base + c + (c >> 3)] - keep[i - 1];
        best = fmaxf(best, sum);
    }
    best *= (1.0f / W);

    // ---- Wave max-reduce, one atomic per wave (win_mean >= 0 -> uint order) ----
    #pragma unroll
    for (int off = 32; off > 0; off >>= 1)
        best = fmaxf(best, __shfl_down(best, off, 64));
    if ((t & 63) == 0)
        atomicMax((unsigned int*)(out + row), __float_as_uint(best));
}

extern "C" void kernel_launch(void* const* d_in, const int* in_sizes, int n_in,
                              void* d_out, int out_size, void* d_ws, size_t ws_size,
                              hipStream_t stream) {
    const float* x = (const float*)d_in[0];
    const float* m = (const float*)d_in[1];
    float* out = (float*)d_out;
    // out is poisoned 0xAA (negative float as bits) -> must zero for atomicMax.
    hipMemsetAsync(out, 0, Bn * sizeof(float), stream);
    winmax_tile<<<Bn * TPB, NT, 0, stream>>>(x, m, out);
}